// Round 1
// baseline (472.753 us; speedup 1.0000x reference)
//
#include <hip/hip_runtime.h>

typedef unsigned short u16;
typedef short bf16x8 __attribute__((ext_vector_type(8)));
typedef float f32x4 __attribute__((ext_vector_type(4)));
typedef u16 u16x4 __attribute__((ext_vector_type(4)));

#define DEVFN static __device__ __forceinline__

constexpr int Bz = 2, Nn = 2048, Mm = 512, Cc = 1536, Hh = 12, HD = 128;
constexpr int Ss = Nn + Mm;                 // 2560
constexpr float EPSV = 1e-6f;
constexpr float SCL = 0.08838834764831845f; // 128^-0.5

DEVFN u16 f2bf(float f) {
  union { float f; unsigned u; } v; v.f = f;
  unsigned r = v.u + 0x7fffu + ((v.u >> 16) & 1u);
  return (u16)(r >> 16);
}

DEVFN void gload16(const void* g, void* l) {
  __builtin_amdgcn_global_load_lds((const __attribute__((address_space(1))) void*)g,
                                   (__attribute__((address_space(3))) void*)l, 16, 0, 0);
}

DEVFN f32x4 mfma16(bf16x8 a, bf16x8 b, f32x4 c) {
  return __builtin_amdgcn_mfma_f32_16x16x32_bf16(a, b, c, 0, 0, 0);
}

// ---------------- prep kernels ----------------

__global__ void k_convert(const float* __restrict__ in, u16* __restrict__ out, int n) {
  int i = (blockIdx.x * blockDim.x + threadIdx.x) * 4;
  if (i < n) {
    float4 v = *(const float4*)(in + i);
    u16x4 o = { f2bf(v.x), f2bf(v.y), f2bf(v.z), f2bf(v.w) };
    *(u16x4*)(out + i) = o;
  }
}

// in: f32 (R x Ccols) row-major -> out: bf16 (Ccols x R)
__global__ void k_transpose_conv(const float* __restrict__ in, u16* __restrict__ out,
                                 int R, int Ccols) {
  __shared__ float t[32][33];
  int c0 = blockIdx.x * 32, r0 = blockIdx.y * 32;
  int lr = threadIdx.x >> 5, lc = threadIdx.x & 31;
#pragma unroll
  for (int i = 0; i < 4; ++i)
    t[lr + 8 * i][lc] = in[(long)(r0 + lr + 8 * i) * Ccols + c0 + lc];
  __syncthreads();
#pragma unroll
  for (int i = 0; i < 4; ++i)
    out[(long)(c0 + lr + 8 * i) * R + r0 + lc] = f2bf(t[lc][lr + 8 * i]);
}

// v (BH, Ss, HD) bf16 -> vt (BH, HD, Ss)
__global__ void k_transpose_v(const u16* __restrict__ in, u16* __restrict__ out) {
  __shared__ u16 t[32][33];
  int bh = blockIdx.z;
  const u16* ib = in + (long)bh * Ss * HD;
  u16* ob = out + (long)bh * HD * Ss;
  int s0 = blockIdx.x * 32, d0 = blockIdx.y * 32;
  int lr = threadIdx.x >> 5, lc = threadIdx.x & 31;
#pragma unroll
  for (int i = 0; i < 4; ++i)
    t[lr + 8 * i][lc] = ib[(long)(s0 + lr + 8 * i) * HD + d0 + lc];
  __syncthreads();
#pragma unroll
  for (int i = 0; i < 4; ++i)
    ob[(long)(d0 + lr + 8 * i) * Ss + s0 + lc] = t[lc][lr + 8 * i];
}

__global__ void k_bias(const float* __restrict__ w, float* __restrict__ bias) {
  int i = blockIdx.x * 256 + threadIdx.x;
  if (i < Bz * Ss) {
    int b = i / Ss, s = i % Ss;
    bias[i] = (s < Nn) ? 0.0f : logf(fmaxf(w[b * Mm + s - Nn], 1e-4f));
  }
}

// ---------------- GEMM (A row-major MxK bf16, Bt = B^T (N x K) bf16) ----------------
// MODE 0: plain + bproj -> f32 out
// MODE 1: qkv epilogue  (s=0 q: RMS+RoPE, s=1 kx: RMS+RoPE, s=2 vx)
// MODE 2: kv  epilogue  (s=0 ky: RMS only -> k[N..], s=1 vy -> v[N..])
template <int MODE>
__global__ __launch_bounds__(256, 2) void k_gemm(
    const u16* __restrict__ A, const u16* __restrict__ Bt,
    int K, int NC, int rowsPerB,
    const float* __restrict__ pos, const float* __restrict__ qnw,
    const float* __restrict__ knw, const float* __restrict__ bprj,
    u16* __restrict__ qout, u16* __restrict__ kout, u16* __restrict__ vout,
    float* __restrict__ fout) {
  __shared__ __align__(16) u16 As[128 * 32];
  __shared__ __align__(16) u16 Bs[128 * 32];
  __shared__ float red[256];
  const int tid = threadIdx.x;
  const int lane = tid & 63;
  const int wid = tid >> 6;
  const int g = lane >> 4, cl = lane & 15;
  const int wr = wid >> 1, wc = wid & 1;
  const long m0 = (long)blockIdx.x * 128, n0 = (long)blockIdx.y * 128;

  f32x4 acc[4][4] = {};

  const int trA = tid >> 2;
  const int db = (tid & 3) ^ (trA & 3);           // source 16B-block (swizzle inverse)
  const char* Ab = (const char*)A + (m0 + trA) * (long)K * 2 + db * 16;
  const char* Bb = (const char*)Bt + (n0 + trA) * (long)K * 2 + db * 16;
  const long rstep = (long)64 * K * 2;
  char* dstA0 = (char*)As + ((tid & ~63) << 4);
  char* dstB0 = (char*)Bs + ((tid & ~63) << 4);

  for (int kt = 0; kt < K / 32; ++kt) {
    __syncthreads();
    gload16(Ab + kt * 64, dstA0);
    gload16(Ab + kt * 64 + rstep, dstA0 + 4096);
    gload16(Bb + kt * 64, dstB0);
    gload16(Bb + kt * 64 + rstep, dstB0 + 4096);
    __syncthreads();
    bf16x8 af[4], bfr[4];
#pragma unroll
    for (int m = 0; m < 4; ++m) {
      int row = wr * 64 + m * 16 + cl;
      af[m] = *(const bf16x8*)((const char*)As + row * 64 + ((g ^ (row & 3)) << 4));
    }
#pragma unroll
    for (int n = 0; n < 4; ++n) {
      int row = wc * 64 + n * 16 + cl;
      bfr[n] = *(const bf16x8*)((const char*)Bs + row * 64 + ((g ^ (row & 3)) << 4));
    }
#pragma unroll
    for (int m = 0; m < 4; ++m)
#pragma unroll
      for (int n = 0; n < 4; ++n)
        acc[m][n] = mfma16(af[m], bfr[n], acc[m][n]);
  }

  if (MODE == 0) {
#pragma unroll
    for (int n = 0; n < 4; ++n) {
      int col = (int)n0 + wc * 64 + n * 16 + cl;
      float bv = bprj[col];
#pragma unroll
      for (int m = 0; m < 4; ++m)
#pragma unroll
        for (int r = 0; r < 4; ++r) {
          long row = m0 + wr * 64 + m * 16 + 4 * g + r;
          fout[row * NC + col] = acc[m][n][r] + bv;
        }
    }
    return;
  }

  // ---- fused RMS / RoPE epilogue ----
  const int ct = blockIdx.y;
  const int s_idx = ct / Hh, h = ct % Hh;
  const int bb = (int)(m0 / rowsPerB);
  const int bh = bb * Hh + h;
  const int seq0 = (int)(m0 % rowsPerB) + wr * 64;
  const bool do_norm = (MODE == 1) ? (s_idx < 2) : (s_idx == 0);
  const bool do_rope = (MODE == 1) && (s_idx < 2);

  if (do_norm) {
    float rs[4][4];
#pragma unroll
    for (int m = 0; m < 4; ++m)
#pragma unroll
      for (int r = 0; r < 4; ++r) {
        float t = 0.f;
#pragma unroll
        for (int n = 0; n < 4; ++n) t += acc[m][n][r] * acc[m][n][r];
        t += __shfl_xor(t, 1);
        t += __shfl_xor(t, 2);
        t += __shfl_xor(t, 4);
        t += __shfl_xor(t, 8);
        if (cl == 0) red[wc * 128 + wr * 64 + m * 16 + 4 * g + r] = t;
      }
    __syncthreads();
#pragma unroll
    for (int m = 0; m < 4; ++m)
#pragma unroll
      for (int r = 0; r < 4; ++r) {
        int row = wr * 64 + m * 16 + 4 * g + r;
        rs[m][r] = rsqrtf((red[row] + red[128 + row]) * (1.0f / 128.0f) + EPSV);
      }
    const float* nw = (MODE == 1 && s_idx == 0) ? qnw : knw;
#pragma unroll
    for (int n = 0; n < 4; ++n) {
      float nwv = nw[wc * 64 + n * 16 + cl];
#pragma unroll
      for (int m = 0; m < 4; ++m)
#pragma unroll
        for (int r = 0; r < 4; ++r) acc[m][n][r] *= rs[m][r] * nwv;
    }
  }

  if (do_rope && wc == 0) {
#pragma unroll
    for (int m = 0; m < 4; ++m)
#pragma unroll
      for (int r = 0; r < 4; ++r) {
        int seq = seq0 + m * 16 + 4 * g + r;
#pragma unroll
        for (int n = 0; n < 2; ++n) {
          int d = n * 16 + cl;  // 0..31
          float cs = pos[(seq * 32 + d) * 2 + 0];
          float sn = pos[(seq * 32 + d) * 2 + 1];
          float t1 = acc[m][n][r], t2 = acc[m][n + 2][r];
          acc[m][n][r] = t1 * cs - t2 * sn;
          acc[m][n + 2][r] = t1 * sn + t2 * cs;
        }
      }
  }

  u16* ob;
  long sbase;
  if (MODE == 1) {
    if (s_idx == 0) { ob = qout; sbase = (long)bh * Nn; }
    else if (s_idx == 1) { ob = kout; sbase = (long)bh * Ss; }
    else { ob = vout; sbase = (long)bh * Ss; }
  } else {
    ob = (s_idx == 0) ? kout : vout;
    sbase = (long)bh * Ss + Nn;
  }
#pragma unroll
  for (int m = 0; m < 4; ++m)
#pragma unroll
    for (int r = 0; r < 4; ++r) {
      long rowb = (sbase + seq0 + m * 16 + 4 * g + r) * HD;
#pragma unroll
      for (int n = 0; n < 4; ++n)
        ob[rowb + wc * 64 + n * 16 + cl] = f2bf(acc[m][n][r]);
    }
}

// ---------------- flash attention ----------------
// Q (BH,Nn,HD) bf16, K (BH,Ss,HD) bf16, Vt (BH,HD,Ss) bf16, bias (Bz,Ss) f32
// out: (B,N,C) bf16
__global__ __launch_bounds__(256, 2) void k_flash(
    const u16* __restrict__ Q, const u16* __restrict__ K, const u16* __restrict__ Vt,
    const float* __restrict__ bias, u16* __restrict__ Aout) {
  __shared__ __align__(16) u16 Qs[128 * 128];
  __shared__ __align__(16) u16 Ks[64 * 128];
  __shared__ __align__(16) u16 Vs[128 * 64];
  __shared__ __align__(16) u16 Ps[4][32 * 64];
  const int tid = threadIdx.x;
  const int lane = tid & 63;
  const int wid = tid >> 6;
  const int g = lane >> 4, cl = lane & 15;
  const int bh = blockIdx.y, b = bh / Hh, h = bh % Hh;
  const int n0 = blockIdx.x * 128;

  const char* Qg = (const char*)(Q + ((long)bh * Nn + n0) * HD);
  const char* Kg = (const char*)(K + (long)bh * Ss * HD);
  const char* Vg = (const char*)(Vt + (long)bh * HD * Ss);
  const float* bg = bias + b * Ss;

  // stage Q (rowBytes 256, XOR-swizzled source blocks, linear LDS dest)
  {
    int row = tid >> 4;
    int sw = ((tid & 15) ^ (row & 7)) << 4;
#pragma unroll
    for (int i = 0; i < 8; ++i)
      gload16(Qg + (row + i * 16) * 256 + sw, (char*)Qs + i * 4096 + ((tid & ~63) << 4));
  }
  const int krow_s = tid >> 4;
  const char* Ksrc0 = Kg + krow_s * 256 + (((tid & 15) ^ (krow_s & 7)) << 4);
  const int vrow_s = tid >> 3;
  const char* Vsrc0 = Vg + (long)vrow_s * (Ss * 2) + (((tid & 7) ^ (vrow_s & 7)) << 4);
  char* kd0 = (char*)Ks + ((tid & ~63) << 4);
  char* vd0 = (char*)Vs + ((tid & ~63) << 4);

#pragma unroll
  for (int i = 0; i < 4; ++i) gload16(Ksrc0 + i * 16 * 256, kd0 + i * 4096);
#pragma unroll
  for (int i = 0; i < 4; ++i) gload16(Vsrc0 + (long)i * 32 * (Ss * 2), vd0 + i * 4096);
  __syncthreads();

  bf16x8 qf[2][4];
#pragma unroll
  for (int m = 0; m < 2; ++m)
#pragma unroll
    for (int kk = 0; kk < 4; ++kk) {
      int row = wid * 32 + m * 16 + cl;
      qf[m][kk] = *(const bf16x8*)((const char*)Qs + row * 256 + (((kk * 4 + g) ^ (row & 7)) << 4));
    }

  f32x4 ov[2][8] = {};
  float mi[2][4], li[2][4];
#pragma unroll
  for (int m = 0; m < 2; ++m)
#pragma unroll
    for (int r = 0; r < 4; ++r) { mi[m][r] = -3.0e38f; li[m][r] = 0.f; }

  u16* pp = Ps[wid];

  for (int t = 0; t < Ss / 64; ++t) {
    const int kv0 = t * 64;
    f32x4 sc[2][4] = {};
#pragma unroll
    for (int n = 0; n < 4; ++n) {
      int krow = n * 16 + cl;
#pragma unroll
      for (int kk = 0; kk < 4; ++kk) {
        bf16x8 kf = *(const bf16x8*)((const char*)Ks + krow * 256 + (((kk * 4 + g) ^ (krow & 7)) << 4));
#pragma unroll
        for (int m = 0; m < 2; ++m) sc[m][n] = mfma16(qf[m][kk], kf, sc[m][n]);
      }
    }
    float bv[4];
#pragma unroll
    for (int n = 0; n < 4; ++n) bv[n] = bg[kv0 + n * 16 + cl];
    float corr[2][4];
#pragma unroll
    for (int m = 0; m < 2; ++m)
#pragma unroll
      for (int r = 0; r < 4; ++r) {
        float mx = -3.0e38f;
#pragma unroll
        for (int n = 0; n < 4; ++n) {
          float s = sc[m][n][r] * SCL + bv[n];
          sc[m][n][r] = s;
          mx = fmaxf(mx, s);
        }
        mx = fmaxf(mx, __shfl_xor(mx, 1));
        mx = fmaxf(mx, __shfl_xor(mx, 2));
        mx = fmaxf(mx, __shfl_xor(mx, 4));
        mx = fmaxf(mx, __shfl_xor(mx, 8));
        float mnew = fmaxf(mi[m][r], mx);
        float co = __expf(mi[m][r] - mnew);
        mi[m][r] = mnew;
        float rsum = 0.f;
#pragma unroll
        for (int n = 0; n < 4; ++n) {
          float p = __expf(sc[m][n][r] - mnew);
          sc[m][n][r] = p;
          rsum += p;
        }
        rsum += __shfl_xor(rsum, 1);
        rsum += __shfl_xor(rsum, 2);
        rsum += __shfl_xor(rsum, 4);
        rsum += __shfl_xor(rsum, 8);
        li[m][r] = li[m][r] * co + rsum;
        corr[m][r] = co;
      }
#pragma unroll
    for (int m = 0; m < 2; ++m)
#pragma unroll
      for (int nd = 0; nd < 8; ++nd)
#pragma unroll
        for (int r = 0; r < 4; ++r) ov[m][nd][r] *= corr[m][r];

    // P (f32, S-layout) -> bf16 LDS [32][64] swizzled (per-wave private)
#pragma unroll
    for (int m = 0; m < 2; ++m)
#pragma unroll
      for (int n = 0; n < 4; ++n)
#pragma unroll
        for (int r = 0; r < 4; ++r) {
          int prow = m * 16 + 4 * g + r, col = n * 16 + cl;
          pp[prow * 64 + (((col >> 3) ^ (prow & 7)) << 3) + (col & 7)] = f2bf(sc[m][n][r]);
        }
    bf16x8 pf[2][2];
#pragma unroll
    for (int m = 0; m < 2; ++m)
#pragma unroll
      for (int ks = 0; ks < 2; ++ks) {
        int row = m * 16 + cl;
        pf[m][ks] = *(const bf16x8*)((const char*)pp + row * 128 + (((ks * 4 + g) ^ (row & 7)) << 4));
      }
#pragma unroll
    for (int nd = 0; nd < 8; ++nd) {
      int vrow = nd * 16 + cl;
#pragma unroll
      for (int ks = 0; ks < 2; ++ks) {
        bf16x8 vf = *(const bf16x8*)((const char*)Vs + vrow * 128 + (((ks * 4 + g) ^ (vrow & 7)) << 4));
#pragma unroll
        for (int m = 0; m < 2; ++m) ov[m][nd] = mfma16(pf[m][ks], vf, ov[m][nd]);
      }
    }
    if (t + 1 < Ss / 64) {
      __syncthreads();
      const long kn = (long)(t + 1) * 64;
#pragma unroll
      for (int i = 0; i < 4; ++i) gload16(Ksrc0 + kn * 256 + i * 16 * 256, kd0 + i * 4096);
#pragma unroll
      for (int i = 0; i < 4; ++i) gload16(Vsrc0 + kn * 2 + (long)i * 32 * (Ss * 2), vd0 + i * 4096);
      __syncthreads();
    }
  }

#pragma unroll
  for (int m = 0; m < 2; ++m)
#pragma unroll
    for (int r = 0; r < 4; ++r) {
      float inv = 1.0f / li[m][r];
      long row = (long)b * Nn + n0 + wid * 32 + m * 16 + 4 * g + r;
      long base = row * Cc + h * HD;
#pragma unroll
      for (int nd = 0; nd < 8; ++nd)
        Aout[base + nd * 16 + cl] = f2bf(ov[m][nd][r] * inv);
    }
}

// ---------------- launcher ----------------

extern "C" void kernel_launch(void* const* d_in, const int* in_sizes, int n_in,
                              void* d_out, int out_size, void* d_ws, size_t ws_size,
                              hipStream_t stream) {
  const float* x = (const float*)d_in[0];
  const float* y = (const float*)d_in[1];
  const float* pos = (const float*)d_in[2];
  const float* ytw = (const float*)d_in[3];
  const float* Wqkv = (const float*)d_in[4];
  const float* Wkv = (const float*)d_in[5];
  const float* qnw = (const float*)d_in[6];
  const float* knw = (const float*)d_in[7];
  const float* Wproj = (const float*)d_in[8];
  const float* bproj = (const float*)d_in[9];
  float* out = (float*)d_out;
  char* ws = (char*)d_ws;

  size_t o = 0;
  auto take = [&](size_t b) {
    char* p = ws + o;
    o += (b + 255) & ~(size_t)255;
    return p;
  };
  u16* xb = (u16*)take((size_t)Bz * Nn * Cc * 2);
  u16* yb = (u16*)take((size_t)Bz * Mm * Cc * 2);
  u16* wqkvt = (u16*)take((size_t)3 * Cc * Cc * 2);
  u16* wkvt = (u16*)take((size_t)2 * Cc * Cc * 2);
  u16* wprjt = (u16*)take((size_t)Cc * Cc * 2);
  u16* qb = (u16*)take((size_t)Bz * Hh * Nn * HD * 2);
  u16* kb = (u16*)take((size_t)Bz * Hh * Ss * HD * 2);
  u16* vb = (u16*)take((size_t)Bz * Hh * Ss * HD * 2);
  u16* vtb = (u16*)take((size_t)Bz * Hh * Ss * HD * 2);
  u16* ab = (u16*)take((size_t)Bz * Nn * Cc * 2);
  float* bias = (float*)take((size_t)Bz * Ss * 4);

  k_convert<<<dim3(Bz * Nn * Cc / 1024), 256, 0, stream>>>(x, xb, Bz * Nn * Cc);
  k_convert<<<dim3(Bz * Mm * Cc / 1024), 256, 0, stream>>>(y, yb, Bz * Mm * Cc);
  k_transpose_conv<<<dim3(3 * Cc / 32, Cc / 32), 256, 0, stream>>>(Wqkv, wqkvt, Cc, 3 * Cc);
  k_transpose_conv<<<dim3(2 * Cc / 32, Cc / 32), 256, 0, stream>>>(Wkv, wkvt, Cc, 2 * Cc);
  k_transpose_conv<<<dim3(Cc / 32, Cc / 32), 256, 0, stream>>>(Wproj, wprjt, Cc, Cc);
  k_bias<<<dim3((Bz * Ss + 255) / 256), 256, 0, stream>>>(ytw, bias);
  k_gemm<1><<<dim3(Bz * Nn / 128, 3 * Cc / 128), 256, 0, stream>>>(
      xb, wqkvt, Cc, 3 * Cc, Nn, pos, qnw, knw, nullptr, qb, kb, vb, nullptr);
  k_gemm<2><<<dim3(Bz * Mm / 128, 2 * Cc / 128), 256, 0, stream>>>(
      yb, wkvt, Cc, 2 * Cc, Mm, pos, qnw, knw, nullptr, nullptr, kb, vb, nullptr);
  k_transpose_v<<<dim3(Ss / 32, HD / 32, Bz * Hh), 256, 0, stream>>>(vb, vtb);
  k_flash<<<dim3(Nn / 128, Bz * Hh), 256, 0, stream>>>(qb, kb, vtb, bias, ab);
  k_gemm<0><<<dim3(Bz * Nn / 128, Cc / 128), 256, 0, stream>>>(
      ab, wprjt, Cc, Cc, Nn, nullptr, nullptr, nullptr, bproj, nullptr, nullptr, nullptr, out);
}